// Round 2
// baseline (193.888 us; speedup 1.0000x reference)
//
#include <hip/hip_runtime.h>
#include <hip/hip_bf16.h>

#define SEQ   2048
#define EMB   1024
#define NHEAD 16
#define DHEAD 64
#define BATCH 2
#define MTOT  (BATCH*SEQ)   // 4096
#define QT    64            // queries per attention block (r2: 128->64)
#define KT    64            // keys per tile

typedef __attribute__((ext_vector_type(8))) short s8v;   // 8 bf16 (4 VGPRs)
typedef __attribute__((ext_vector_type(4))) short s4v;   // 4 bf16 (8 B)
typedef __attribute__((ext_vector_type(4))) float f4v;   // mfma accum

__device__ __forceinline__ short f2b(float f) {
    union { float fl; unsigned u; } v; v.fl = f;
    unsigned u = v.u;
    u = (u + 0x7fffu + ((u >> 16) & 1u)) >> 16;   // round-to-nearest-even
    return (short)u;
}
// packed fp32x2 -> bf16x2 (v_cvt_pk_bf16_f32); rounded values also feed the
// softmax denominator (consistency => rounding-mode-agnostic).
__device__ __forceinline__ unsigned pk2(float a, float b) {
    union { __hip_bfloat162 h; unsigned u; } c;
    c.h = __float22bfloat162_rn(float2{a, b});
    return c.u;
}

#if __has_builtin(__builtin_amdgcn_exp2f)
__device__ __forceinline__ float exp2_fast(float x) { return __builtin_amdgcn_exp2f(x); }
#else
__device__ __forceinline__ float exp2_fast(float x) { return exp2f(x); }
#endif

// gfx950 cross-lane half-swaps: dst upper part <-> src lower part.
// pl32: dst[32:63] <-> src[0:31].  pl16: dst[16:31]<->src[0:15], dst[48:63]<->src[32:47].
__device__ __forceinline__ void pl32swap(unsigned &a, unsigned &b) {
    asm("v_permlane32_swap_b32 %0, %1" : "+v"(a), "+v"(b));
}
__device__ __forceinline__ void pl16swap(unsigned &a, unsigned &b) {
    asm("v_permlane16_swap_b32 %0, %1" : "+v"(a), "+v"(b));
}

// Raw workgroup barrier: LDS-visibility only (lgkmcnt drain), does NOT drain
// vmcnt — outstanding global prefetch loads stay in flight across it.
__device__ __forceinline__ void bar_lds() {
    asm volatile("s_waitcnt lgkmcnt(0)\n\ts_barrier" ::: "memory");
}

// async global->LDS DMA, 16 B/lane; LDS dest = wave-uniform base + lane*16.
__device__ __forceinline__ void gl_lds16(const short* g, short* l) {
    __builtin_amdgcn_global_load_lds(
        (const __attribute__((address_space(1))) void*)g,
        (__attribute__((address_space(3))) void*)l, 16, 0, 0);
}

// ---- fp32 -> bf16 convert + chunk swizzle ----
// Output rows are 1024 bf16 = 16 aligned 128B groups of 8 16B-chunks.
// Chunk c of row r is stored at slot (c&~7) | ((c&7) ^ (r&7)) so that
// global_load_lds' contiguous DMA lands a bank-uniform LDS image.
__global__ __launch_bounds__(256)
void cvt_swz(const float* __restrict__ s0, const float* __restrict__ s1,
             const float* __restrict__ s2, const float* __restrict__ s3,
             const float* __restrict__ s4,
             short* __restrict__ d0, short* __restrict__ d1,
             short* __restrict__ d2, short* __restrict__ d3,
             short* __restrict__ d4)
{
    const int seg = blockIdx.y;
    const float* s = seg == 0 ? s0 : seg == 1 ? s1 : seg == 2 ? s2 : seg == 3 ? s3 : s4;
    short*       d = seg == 0 ? d0 : seg == 1 ? d1 : seg == 2 ? d2 : seg == 3 ? d3 : d4;
    const int nchunk = (seg == 0 ? MTOT * EMB : EMB * EMB) / 8;   // 16B chunks
    const int stride = gridDim.x * 256;
    for (int i = blockIdx.x * 256 + threadIdx.x; i < nchunk; i += stride) {
        const int row = i >> 7;         // 128 chunks per 1024-col row
        const int c   = i & 127;
        const float4 v0 = *(const float4*)(s + (size_t)i * 8);
        const float4 v1 = *(const float4*)(s + (size_t)i * 8 + 4);
        s8v o;
        o[0] = f2b(v0.x); o[1] = f2b(v0.y); o[2] = f2b(v0.z); o[3] = f2b(v0.w);
        o[4] = f2b(v1.x); o[5] = f2b(v1.y); o[6] = f2b(v1.z); o[7] = f2b(v1.w);
        const int cp = (c & ~7) | ((c & 7) ^ (row & 7));
        *(s8v*)(d + (size_t)row * EMB + cp * 8) = o;
    }
}

// NT GEMM via global_load_lds (m97 structure): C = A*W^T + bias.
// A, W are bf16 with swizzled 16B chunks (see cvt_swz). LDS rows unpadded
// (128 B); frag reads address slot (kk*4+quad)^(l16&7) -> bank-uniform.
// FUSED3: 3 matrices (QKV); mat 2 writes V transposed per-head [b][h][d][s].
// mat 0 (Q) output is prescaled by 0.125*log2(e) so attention uses exp2.
template<int NT, bool FUSED3>
__global__ __launch_bounds__(256, 3)
void gemm_bb3(const short* __restrict__ A,
              const short* __restrict__ W0, const short* __restrict__ W1, const short* __restrict__ W2,
              const float* __restrict__ B0, const float* __restrict__ B1, const float* __restrict__ B2,
              void* __restrict__ C0, void* __restrict__ C1, void* __restrict__ C2)
{
    constexpr int JN = NT / 32;
    const int K = EMB, N = EMB;
    const int ntiles = EMB / NT;
    const int mat = blockIdx.x / ntiles;
    const int n0  = (blockIdx.x % ntiles) * NT;
    const int m0  = blockIdx.y * 128;
    const short* W  = (mat == 0) ? W0 : (mat == 1 ? W1 : W2);
    const float* Bi = (mat == 0) ? B0 : (mat == 1 ? B1 : B2);
    void*        C  = (mat == 0) ? C0 : (mat == 1 ? C1 : C2);
    const float qscale = (FUSED3 && mat == 0) ? 0.18033688f : 1.0f;  // 1/8*log2e

    __shared__ __align__(16) short As[128 * 64];
    __shared__ __align__(16) short Ws[NT * 64];

    const int tid  = threadIdx.x;
    const int lane = tid & 63;
    const int wave = tid >> 6;
    const int quad = lane >> 4;
    const int l16  = lane & 15;
    const int l8   = l16 & 7;
    const int wm   = wave >> 1;
    const int wn   = wave & 1;

    f4v acc[4][JN] = {};

    const int srow = lane >> 3;    // staging row within 8-row group
    const int scol = (lane & 7) * 8;

    for (int k0 = 0; k0 < K; k0 += 64) {
        // ---- async DMA staging: A rows wave*32.., W rows wave*(NT/4).. ----
        #pragma unroll
        for (int p = 0; p < 4; ++p) {
            const int rbase = wave * 32 + p * 8;
            gl_lds16(A + (size_t)(m0 + rbase + srow) * K + k0 + scol,
                     As + rbase * 64);
        }
        #pragma unroll
        for (int p = 0; p < NT / 32; ++p) {
            const int rbase = wave * (NT / 4) + p * 8;
            gl_lds16(W + (size_t)(n0 + rbase + srow) * K + k0 + scol,
                     Ws + rbase * 64);
        }
        __syncthreads();   // drains the DMA (vmcnt) + barrier

        #pragma unroll
        for (int kk = 0; kk < 2; ++kk) {
            const int slot = ((kk * 4 + quad) ^ l8) * 8;
            s8v af[4], wf[JN];
            #pragma unroll
            for (int i = 0; i < 4; ++i)
                af[i] = *(const s8v*)(As + (wm * 64 + i * 16 + l16) * 64 + slot);
            #pragma unroll
            for (int j = 0; j < JN; ++j)
                wf[j] = *(const s8v*)(Ws + (wn * (NT / 2) + j * 16 + l16) * 64 + slot);
            #pragma unroll
            for (int i = 0; i < 4; ++i)
                #pragma unroll
                for (int j = 0; j < JN; ++j)
                    acc[i][j] = __builtin_amdgcn_mfma_f32_16x16x32_bf16(
                        af[i], wf[j], acc[i][j], 0, 0, 0);
        }
        __syncthreads();   // all waves done reading before next overwrite
    }

    // C/D layout: col = lane&15 (n), row = quad*4+reg (m)   [m89-verified]
    #pragma unroll
    for (int j = 0; j < JN; ++j) {
        const int n = n0 + wn * (NT / 2) + j * 16 + l16;
        const float bv = Bi[n];
        #pragma unroll
        for (int i = 0; i < 4; ++i) {
            const int mb = m0 + wm * 64 + i * 16 + quad * 4;
            if (FUSED3 && mat == 2) {
                const int bb = mb >> 11, s = mb & 2047;
                s4v ov;
                #pragma unroll
                for (int rr = 0; rr < 4; ++rr) ov[rr] = f2b(acc[i][j][rr] + bv);
                *(s4v*)((short*)C + ((size_t)(bb * 1024 + n)) * SEQ + s) = ov;
            } else if (FUSED3) {
                #pragma unroll
                for (int rr = 0; rr < 4; ++rr)
                    ((short*)C)[(size_t)(mb + rr) * N + n] = f2b((acc[i][j][rr] + bv) * qscale);
            } else {
                #pragma unroll
                for (int rr = 0; rr < 4; ++rr)
                    ((float*)C)[(size_t)(mb + rr) * N + n] = acc[i][j][rr] + bv;
            }
        }
    }
}

// MFMA flash attention v6.
// vs v5: (1) QT 128->64: grid 512->1024 blocks = 4 blocks/CU (was 2) for
// latency hiding; (2) the P round-trip through LDS (Pt) is replaced by an
// in-register all-to-all over lane bits 4/5 using v_permlane{32,16}_swap_b32:
// QK^T C-layout value at quad(b4,b5), reg (j,r2) must reach lane
// (b4'=b5, b5'=j&1), reg (kk=j>>1, s=2*b4+r2) — exactly two butterfly
// stages (8 instrs/tile, replaces 4 ds_write + 2 ds_read + lgkm waits);
// (3) XCD head-affinity block swizzle: each XCD gets 4 (b,h) combos so its
// K/V working set (2 MB) fits the 4 MB XCD L2 -> HBM re-fetch collapses.
// LDS: 32 KB (K/V double-buffer only). Denominator via ones-MFMA as v5.
__global__ __launch_bounds__(256, 4)
void attn_mfma6(const short* Q, const short* __restrict__ Kg,
                const short* __restrict__ Vt, short* O)
{
    // dispatch i -> XCD i&7 (round-robin). Give each XCD 4 (b,h) combos.
    const int i    = blockIdx.x;          // 1024 blocks
    const int xcd  = i & 7;
    const int slot = i >> 3;              // 0..127
    const int combo = xcd * 4 + (slot >> 5);   // (b,h) 0..31
    const int qb = slot & 31;
    const int h  = combo & 15;
    const int b  = combo >> 4;
    const int q0 = qb * QT;

    const int tid  = threadIdx.x;
    const int lane = tid & 63;
    const int wave = tid >> 6;
    const int quad = lane >> 4;
    const int l16  = lane & 15;
    const int l8   = l16 & 7;

    __shared__ __align__(16) short Ks[2][64 * 64];   // [key][d]   swizzled
    __shared__ __align__(16) short Vs[2][64 * 64];   // [d][key]   swizzled

    // Q B-frags (prescaled by 0.125*log2e): wave handles 16 q-rows
    s8v qf[2];
    #pragma unroll
    for (int kk = 0; kk < 2; ++kk)
        qf[kk] = *(const s8v*)(Q + (size_t)(b * SEQ + q0 + wave * 16 + l16) * EMB
                                 + h * DHEAD + kk * 32 + quad * 8);

    f4v oacc[4] = {};   // [j: d-block] -> O^T[d][q]
    f4v sacc    = {};   // ones-MFMA row sums (col = q, all rows equal)
    s8v onef;
    #pragma unroll
    for (int e = 0; e < 8; ++e) onef[e] = (short)0x3F80;   // bf16 1.0

    const int c = tid & 7, r = tid >> 3;
    const int swz = (c ^ (r & 7)) * 8;          // staging chunk swizzle
    const size_t kbase = (size_t)(b * SEQ) * EMB + h * DHEAD;
    const size_t vbase = (size_t)((b * NHEAD + h) * DHEAD) * SEQ;

    // prologue: prefetch tile 0
    s8v ka[2], va[2];
    #pragma unroll
    for (int p = 0; p < 2; ++p) {
        ka[p] = *(const s8v*)(Kg + kbase + (size_t)(r + p * 32) * EMB + c * 8);
        va[p] = *(const s8v*)(Vt + vbase + (size_t)(r + p * 32) * SEQ + c * 8);
    }

    for (int t = 0; t < SEQ / KT; ++t) {
        const int buf = t & 1;
        short* KsB = Ks[buf];
        short* VsB = Vs[buf];

        // write current tile from regs, swizzled ((r+p*32)&7 == r&7)
        #pragma unroll
        for (int p = 0; p < 2; ++p) {
            *(s8v*)(KsB + (r + p * 32) * 64 + swz) = ka[p];
            *(s8v*)(VsB + (r + p * 32) * 64 + swz) = va[p];
        }
        // async prefetch of next tile (stays in flight across the barrier)
        if (t + 1 < SEQ / KT) {
            const int kt2 = (t + 1) * KT;
            #pragma unroll
            for (int p = 0; p < 2; ++p) {
                ka[p] = *(const s8v*)(Kg + kbase + (size_t)(kt2 + r + p * 32) * EMB + c * 8);
                va[p] = *(const s8v*)(Vt + vbase + (size_t)(r + p * 32) * SEQ + kt2 + c * 8);
            }
        }
        bar_lds();   // tile visible; prefetch NOT drained

        // ---- S^T[key][q] = K · Q^T (already in log2 domain) ----
        f4v sc[4] = {};
        #pragma unroll
        for (int kk = 0; kk < 2; ++kk) {
            const int ko = ((kk * 4 + quad) ^ l8) * 8;
            s8v kf[4];
            #pragma unroll
            for (int j = 0; j < 4; ++j)
                kf[j] = *(const s8v*)(KsB + (j * 16 + l16) * 64 + ko);
            #pragma unroll
            for (int j = 0; j < 4; ++j)
                sc[j] = __builtin_amdgcn_mfma_f32_16x16x32_bf16(
                    kf[j], qf[kk], sc[j], 0, 0, 0);
        }

        // ---- p = 2^s, pack to bf16 pairs: u[j][r2] = keys (j*16+quad*4+2r2, +1) ----
        unsigned u[4][2];
        #pragma unroll
        for (int j = 0; j < 4; ++j) {
            u[j][0] = pk2(exp2_fast(sc[j][0]), exp2_fast(sc[j][1]));
            u[j][1] = pk2(exp2_fast(sc[j][2]), exp2_fast(sc[j][3]));
        }

        // ---- in-register all-to-all over lane bits 4/5 (see header) ----
        #pragma unroll
        for (int r2 = 0; r2 < 2; ++r2) {
            pl32swap(u[0][r2], u[1][r2]);   // stage A: b5' = j&1
            pl32swap(u[2][r2], u[3][r2]);
            pl16swap(u[0][r2], u[1][r2]);   // stage B: b4' = orig b5
            pl16swap(u[2][r2], u[3][r2]);
        }
        union { unsigned uu[4]; s8v s; } pfa, pfb;
        pfa.uu[0] = u[0][0]; pfa.uu[1] = u[0][1]; pfa.uu[2] = u[1][0]; pfa.uu[3] = u[1][1];
        pfb.uu[0] = u[2][0]; pfb.uu[1] = u[2][1]; pfb.uu[2] = u[3][0]; pfb.uu[3] = u[3][1];

        // ---- O^T[d][q] += V^T[d][key] · P^T ; row sums via ones-MFMA ----
        #pragma unroll
        for (int kk = 0; kk < 2; ++kk) {
            const s8v pf = kk ? pfb.s : pfa.s;
            sacc = __builtin_amdgcn_mfma_f32_16x16x32_bf16(onef, pf, sacc, 0, 0, 0);
            const int ko = ((kk * 4 + quad) ^ l8) * 8;
            #pragma unroll
            for (int j = 0; j < 4; ++j) {
                const s8v vf = *(const s8v*)(VsB + (j * 16 + l16) * 64 + ko);
                oacc[j] = __builtin_amdgcn_mfma_f32_16x16x32_bf16(
                    vf, pf, oacc[j], 0, 0, 0);
            }
        }
    }

    // ---- denominator: every row of sacc holds the full sum for col q ----
    const float inv = 1.0f / sacc[0];

    // ---- O^T C-layout -> LDS [q][d] packed, swizzled (reuse Ks buf 0;
    //      safe: epilogue is past the t=31 barrier, laggards read buf 1) ----
    short* Os = (short*)Ks;   // 64 rows x 64 shorts = 8 KB
    #pragma unroll
    for (int j = 0; j < 4; ++j) {
        union { unsigned uu[2]; s4v s; } ov;
        ov.uu[0] = pk2(oacc[j][0] * inv, oacc[j][1] * inv);
        ov.uu[1] = pk2(oacc[j][2] * inv, oacc[j][3] * inv);
        const int pc = ((j * 2 + (quad >> 1)) ^ l8) * 8 + (quad & 1) * 4;
        *(s4v*)(Os + (wave * 16 + l16) * 64 + pc) = ov.s;
    }
    bar_lds();

    // ---- coalesced store: LDS swizzle cancels the output chunk swizzle ----
    const int row = tid >> 2;            // 0..63
    const int cb  = (tid & 3) * 2;       // two physical chunks per thread
    #pragma unroll
    for (int c4 = 0; c4 < 2; ++c4) {
        const int pcc = cb + c4;
        const s8v tt = *(const s8v*)(Os + row * 64 + pcc * 8);
        *(s8v*)(O + (size_t)(b * SEQ + q0 + row) * EMB + h * DHEAD + pcc * 8) = tt;
    }
}

extern "C" void kernel_launch(void* const* d_in, const int* in_sizes, int n_in,
                              void* d_out, int out_size, void* d_ws, size_t ws_size,
                              hipStream_t stream)
{
    const float* x  = (const float*)d_in[0];
    const float* Wq = (const float*)d_in[1];
    const float* bq = (const float*)d_in[2];
    const float* Wk = (const float*)d_in[3];
    const float* bk = (const float*)d_in[4];
    const float* Wv = (const float*)d_in[5];
    const float* bv = (const float*)d_in[6];
    const float* Wo = (const float*)d_in[7];
    const float* bo = (const float*)d_in[8];
    float* out = (float*)d_out;   // fp32 output

    short* xb  = (short*)d_ws;                       // 4096x1024 bf16, swizzled
    short* Wqb = xb  + (size_t)MTOT * EMB;           // swizzled
    short* Wkb = Wqb + (size_t)EMB * EMB;
    short* Wvb = Wkb + (size_t)EMB * EMB;
    short* Wob = Wvb + (size_t)EMB * EMB;
    short* Qw  = Wob + (size_t)EMB * EMB;            // [token][1024] (Q: plain;
                                                     //  then O: swizzled)
    short* Kw  = Qw  + (size_t)MTOT * EMB;           // [token][1024] plain
    short* Vtw = Kw  + (size_t)MTOT * EMB;           // [b][h][d][s] plain

    cvt_swz<<<dim3(512, 5), 256, 0, stream>>>(x, Wq, Wk, Wv, Wo,
                                              xb, Wqb, Wkb, Wvb, Wob);

    gemm_bb3<128, true><<<dim3(24, 32), 256, 0, stream>>>(
        xb, Wqb, Wkb, Wvb, bq, bk, bv, Qw, Kw, Vtw);

    attn_mfma6<<<dim3(BATCH * NHEAD * (SEQ / QT)), 256, 0, stream>>>(Qw, Kw, Vtw, Qw);

    gemm_bb3<64, false><<<dim3(16, 32), 256, 0, stream>>>(
        Qw, Wob, Wob, Wob, bo, bo, bo, out, out, out);
}

// Round 3
// 185.266 us; speedup vs baseline: 1.0465x; 1.0465x over previous
//
#include <hip/hip_runtime.h>
#include <hip/hip_bf16.h>

#define SEQ   2048
#define EMB   1024
#define NHEAD 16
#define DHEAD 64
#define BATCH 2
#define MTOT  (BATCH*SEQ)   // 4096
#define QT    128           // queries per attention block (r3: back to 128)
#define KT    64            // keys per tile
#define NTILE (SEQ/KT)      // 32

typedef __attribute__((ext_vector_type(8))) short s8v;   // 8 bf16 (4 VGPRs)
typedef __attribute__((ext_vector_type(4))) short s4v;   // 4 bf16 (8 B)
typedef __attribute__((ext_vector_type(4))) float f4v;   // mfma accum

__device__ __forceinline__ short f2b(float f) {
    union { float fl; unsigned u; } v; v.fl = f;
    unsigned u = v.u;
    u = (u + 0x7fffu + ((u >> 16) & 1u)) >> 16;   // round-to-nearest-even
    return (short)u;
}
// packed fp32x2 -> bf16x2 (v_cvt_pk_bf16_f32); rounded values also feed the
// softmax denominator (consistency => rounding-mode-agnostic).
__device__ __forceinline__ unsigned pk2(float a, float b) {
    union { __hip_bfloat162 h; unsigned u; } c;
    c.h = __float22bfloat162_rn(float2{a, b});
    return c.u;
}

#if __has_builtin(__builtin_amdgcn_exp2f)
__device__ __forceinline__ float exp2_fast(float x) { return __builtin_amdgcn_exp2f(x); }
#else
__device__ __forceinline__ float exp2_fast(float x) { return exp2f(x); }
#endif

// gfx950 cross-lane half-swaps: dst upper part <-> src lower part.
__device__ __forceinline__ void pl32swap(unsigned &a, unsigned &b) {
    asm("v_permlane32_swap_b32 %0, %1" : "+v"(a), "+v"(b));
}
__device__ __forceinline__ void pl16swap(unsigned &a, unsigned &b) {
    asm("v_permlane16_swap_b32 %0, %1" : "+v"(a), "+v"(b));
}

// Raw workgroup barrier: LDS-visibility only (lgkmcnt drain), does NOT drain
// vmcnt — outstanding global prefetch loads stay in flight across it.
__device__ __forceinline__ void bar_lds() {
    asm volatile("s_waitcnt lgkmcnt(0)\n\ts_barrier" ::: "memory");
}

// async global->LDS DMA, 16 B/lane; LDS dest = wave-uniform base + lane*16.
__device__ __forceinline__ void gl_lds16(const short* g, short* l) {
    __builtin_amdgcn_global_load_lds(
        (const __attribute__((address_space(1))) void*)g,
        (__attribute__((address_space(3))) void*)l, 16, 0, 0);
}

// ---- fp32 -> bf16 convert + chunk swizzle ----
// Output rows are 1024 bf16 = 16 aligned 128B groups of 8 16B-chunks.
// Chunk c of row r is stored at slot (c&~7) | ((c&7) ^ (r&7)) so that
// global_load_lds' contiguous DMA lands a bank-uniform LDS image.
__global__ __launch_bounds__(256)
void cvt_swz(const float* __restrict__ s0, const float* __restrict__ s1,
             const float* __restrict__ s2, const float* __restrict__ s3,
             const float* __restrict__ s4,
             short* __restrict__ d0, short* __restrict__ d1,
             short* __restrict__ d2, short* __restrict__ d3,
             short* __restrict__ d4)
{
    const int seg = blockIdx.y;
    const float* s = seg == 0 ? s0 : seg == 1 ? s1 : seg == 2 ? s2 : seg == 3 ? s3 : s4;
    short*       d = seg == 0 ? d0 : seg == 1 ? d1 : seg == 2 ? d2 : seg == 3 ? d3 : d4;
    const int nchunk = (seg == 0 ? MTOT * EMB : EMB * EMB) / 8;   // 16B chunks
    const int stride = gridDim.x * 256;
    for (int i = blockIdx.x * 256 + threadIdx.x; i < nchunk; i += stride) {
        const int row = i >> 7;         // 128 chunks per 1024-col row
        const int c   = i & 127;
        const float4 v0 = *(const float4*)(s + (size_t)i * 8);
        const float4 v1 = *(const float4*)(s + (size_t)i * 8 + 4);
        s8v o;
        o[0] = f2b(v0.x); o[1] = f2b(v0.y); o[2] = f2b(v0.z); o[3] = f2b(v0.w);
        o[4] = f2b(v1.x); o[5] = f2b(v1.y); o[6] = f2b(v1.z); o[7] = f2b(v1.w);
        const int cp = (c & ~7) | ((c & 7) ^ (row & 7));
        *(s8v*)(d + (size_t)row * EMB + cp * 8) = o;
    }
}

// NT GEMM via global_load_lds (m97 structure): C = A*W^T + bias.
// A, W are bf16 with swizzled 16B chunks (see cvt_swz). LDS rows unpadded
// (128 B); frag reads address slot (kk*4+quad)^(l16&7) -> bank-uniform.
// FUSED3: 3 matrices (QKV); mat 2 writes V transposed per-head [b][h][d][s].
// mat 0 (Q) output is prescaled by 0.125*log2(e) so attention uses exp2.
template<int NT, bool FUSED3>
__global__ __launch_bounds__(256, 3)
void gemm_bb3(const short* __restrict__ A,
              const short* __restrict__ W0, const short* __restrict__ W1, const short* __restrict__ W2,
              const float* __restrict__ B0, const float* __restrict__ B1, const float* __restrict__ B2,
              void* __restrict__ C0, void* __restrict__ C1, void* __restrict__ C2)
{
    constexpr int JN = NT / 32;
    const int K = EMB, N = EMB;
    const int ntiles = EMB / NT;
    const int mat = blockIdx.x / ntiles;
    const int n0  = (blockIdx.x % ntiles) * NT;
    const int m0  = blockIdx.y * 128;
    const short* W  = (mat == 0) ? W0 : (mat == 1 ? W1 : W2);
    const float* Bi = (mat == 0) ? B0 : (mat == 1 ? B1 : B2);
    void*        C  = (mat == 0) ? C0 : (mat == 1 ? C1 : C2);
    const float qscale = (FUSED3 && mat == 0) ? 0.18033688f : 1.0f;  // 1/8*log2e

    __shared__ __align__(16) short As[128 * 64];
    __shared__ __align__(16) short Ws[NT * 64];

    const int tid  = threadIdx.x;
    const int lane = tid & 63;
    const int wave = tid >> 6;
    const int quad = lane >> 4;
    const int l16  = lane & 15;
    const int l8   = l16 & 7;
    const int wm   = wave >> 1;
    const int wn   = wave & 1;

    f4v acc[4][JN] = {};

    const int srow = lane >> 3;    // staging row within 8-row group
    const int scol = (lane & 7) * 8;

    for (int k0 = 0; k0 < K; k0 += 64) {
        // ---- async DMA staging: A rows wave*32.., W rows wave*(NT/4).. ----
        #pragma unroll
        for (int p = 0; p < 4; ++p) {
            const int rbase = wave * 32 + p * 8;
            gl_lds16(A + (size_t)(m0 + rbase + srow) * K + k0 + scol,
                     As + rbase * 64);
        }
        #pragma unroll
        for (int p = 0; p < NT / 32; ++p) {
            const int rbase = wave * (NT / 4) + p * 8;
            gl_lds16(W + (size_t)(n0 + rbase + srow) * K + k0 + scol,
                     Ws + rbase * 64);
        }
        __syncthreads();   // drains the DMA (vmcnt) + barrier

        #pragma unroll
        for (int kk = 0; kk < 2; ++kk) {
            const int slot = ((kk * 4 + quad) ^ l8) * 8;
            s8v af[4], wf[JN];
            #pragma unroll
            for (int i = 0; i < 4; ++i)
                af[i] = *(const s8v*)(As + (wm * 64 + i * 16 + l16) * 64 + slot);
            #pragma unroll
            for (int j = 0; j < JN; ++j)
                wf[j] = *(const s8v*)(Ws + (wn * (NT / 2) + j * 16 + l16) * 64 + slot);
            #pragma unroll
            for (int i = 0; i < 4; ++i)
                #pragma unroll
                for (int j = 0; j < JN; ++j)
                    acc[i][j] = __builtin_amdgcn_mfma_f32_16x16x32_bf16(
                        af[i], wf[j], acc[i][j], 0, 0, 0);
        }
        __syncthreads();   // all waves done reading before next overwrite
    }

    // C/D layout: col = lane&15 (n), row = quad*4+reg (m)   [m89-verified]
    #pragma unroll
    for (int j = 0; j < JN; ++j) {
        const int n = n0 + wn * (NT / 2) + j * 16 + l16;
        const float bv = Bi[n];
        #pragma unroll
        for (int i = 0; i < 4; ++i) {
            const int mb = m0 + wm * 64 + i * 16 + quad * 4;
            if (FUSED3 && mat == 2) {
                const int bb = mb >> 11, s = mb & 2047;
                s4v ov;
                #pragma unroll
                for (int rr = 0; rr < 4; ++rr) ov[rr] = f2b(acc[i][j][rr] + bv);
                *(s4v*)((short*)C + ((size_t)(bb * 1024 + n)) * SEQ + s) = ov;
            } else if (FUSED3) {
                #pragma unroll
                for (int rr = 0; rr < 4; ++rr)
                    ((short*)C)[(size_t)(mb + rr) * N + n] = f2b((acc[i][j][rr] + bv) * qscale);
            } else {
                #pragma unroll
                for (int rr = 0; rr < 4; ++rr)
                    ((float*)C)[(size_t)(mb + rr) * N + n] = acc[i][j][rr] + bv;
            }
        }
    }
}

// MFMA flash attention v7.
// vs v6: (1) QT back to 128 but with 512 threads (8 waves x 16 q-rows) ->
// grid 512 blocks = 2 blocks/CU x 8 waves = 16 waves/CU, and per-block
// staging is amortized over 2x the compute; (2) K/V staging now uses
// global_load_lds DMA with PRE-SWIZZLED per-lane global source addresses
// (m173 pattern): LDS dest stays linear, source chunk = c ^ r, so the
// bank-uniform read swizzle is preserved with zero reg-staging VALU.
// Waves 0-3 stage K (2x1KB DMA each), waves 4-7 stage V. Pipeline: issue
// DMA(t+1) right AFTER the tile-t __syncthreads (compute(t-1) globally done
// by barrier => its buffer is free), so the prefetch stays in flight across
// the whole compute(t) phase and the barrier's vmcnt(0) only ever drains
// the tile that is needed next. P all-to-all via permlane (v6); denominator
// via ones-MFMA (v5); XCD head-affinity swizzle (v6).
__global__ __launch_bounds__(512, 4)
void attn_mfma7(const short* Q, const short* __restrict__ Kg,
                const short* __restrict__ Vt, short* O)
{
    // dispatch i -> XCD i&7 (round-robin). Give each XCD 4 (b,h) combos.
    const int i    = blockIdx.x;          // 512 blocks
    const int xcd  = i & 7;
    const int slot = i >> 3;              // 0..63
    const int combo = xcd * 4 + (slot >> 4);   // (b,h) 0..31
    const int qb = slot & 15;                  // 16 q-blocks per (b,h)
    const int h  = combo & 15;
    const int b  = combo >> 4;
    const int q0 = qb * QT;

    const int tid  = threadIdx.x;
    const int lane = tid & 63;
    const int wave = tid >> 6;            // 0..7
    const int quad = lane >> 4;
    const int l16  = lane & 15;
    const int l8   = l16 & 7;

    __shared__ __align__(16) short Ks[2][64 * 64];   // [key][d]   swizzled image
    __shared__ __align__(16) short Vs[2][64 * 64];   // [d][key]   swizzled image

    // Q B-frags (prescaled by 0.125*log2e): wave handles 16 q-rows
    s8v qf[2];
    #pragma unroll
    for (int kk = 0; kk < 2; ++kk)
        qf[kk] = *(const s8v*)(Q + (size_t)(b * SEQ + q0 + wave * 16 + l16) * EMB
                                 + h * DHEAD + kk * 32 + quad * 8);

    f4v oacc[4] = {};   // [j: d-block] -> O^T[d][q]
    f4v sacc    = {};   // ones-MFMA row sums (col = q, all rows equal)
    s8v onef;
    #pragma unroll
    for (int e = 0; e < 8; ++e) onef[e] = (short)0x3F80;   // bf16 1.0

    // ---- DMA staging setup: lane (r,c) covers row r, physical chunk c ----
    const int r = lane >> 3, c = lane & 7;
    const int sc8 = (c ^ r) * 8;               // pre-swizzled source chunk
    const bool isK = wave < 4;
    const int wrow = (wave & 3) * 16;          // 16 rows per stager wave
    const size_t kbase = (size_t)(b * SEQ) * EMB + h * DHEAD;
    const size_t vbase = (size_t)((b * NHEAD + h) * DHEAD) * SEQ;
    // per-lane global source for tile 0
    const short* gsrc = isK ? Kg + kbase + (size_t)(wrow + r) * EMB + sc8
                            : Vt + vbase + (size_t)(wrow + r) * SEQ + sc8;
    const size_t gstep8 = isK ? (size_t)8 * EMB : (size_t)8 * SEQ;  // +8 rows
    const size_t tstep  = isK ? (size_t)KT * EMB : (size_t)KT;      // +1 tile
    short* const lbase  = (isK ? (short*)Ks : (short*)Vs) + wrow * 64;

    // prologue: issue DMA for tile 0 into buf 0
    gl_lds16(gsrc,          lbase);
    gl_lds16(gsrc + gstep8, lbase + 8 * 64);
    const short* gnext = gsrc + tstep;

    for (int t = 0; t < NTILE; ++t) {
        const int buf = t & 1;
        __syncthreads();   // vmcnt(0)+barrier: tile t landed everywhere;
                           // compute(t-1) done everywhere -> buf^1 is free
        if (t + 1 < NTILE) {
            short* ldst = lbase + (buf ^ 1) * (64 * 64);
            gl_lds16(gnext,          ldst);
            gl_lds16(gnext + gstep8, ldst + 8 * 64);
            gnext += tstep;
        }
        const short* KsB = Ks[buf];
        const short* VsB = Vs[buf];

        // ---- S^T[key][q] = K · Q^T (already in log2 domain) ----
        f4v sc[4] = {};
        #pragma unroll
        for (int kk = 0; kk < 2; ++kk) {
            const int ko = ((kk * 4 + quad) ^ l8) * 8;
            s8v kf[4];
            #pragma unroll
            for (int j = 0; j < 4; ++j)
                kf[j] = *(const s8v*)(KsB + (j * 16 + l16) * 64 + ko);
            #pragma unroll
            for (int j = 0; j < 4; ++j)
                sc[j] = __builtin_amdgcn_mfma_f32_16x16x32_bf16(
                    kf[j], qf[kk], sc[j], 0, 0, 0);
        }

        // ---- p = 2^s, pack to bf16 pairs ----
        unsigned u[4][2];
        #pragma unroll
        for (int j = 0; j < 4; ++j) {
            u[j][0] = pk2(exp2_fast(sc[j][0]), exp2_fast(sc[j][1]));
            u[j][1] = pk2(exp2_fast(sc[j][2]), exp2_fast(sc[j][3]));
        }

        // ---- in-register all-to-all over lane bits 4/5 ----
        #pragma unroll
        for (int r2 = 0; r2 < 2; ++r2) {
            pl32swap(u[0][r2], u[1][r2]);   // stage A: b5' = j&1
            pl32swap(u[2][r2], u[3][r2]);
            pl16swap(u[0][r2], u[1][r2]);   // stage B: b4' = orig b5
            pl16swap(u[2][r2], u[3][r2]);
        }
        union { unsigned uu[4]; s8v s; } pfa, pfb;
        pfa.uu[0] = u[0][0]; pfa.uu[1] = u[0][1]; pfa.uu[2] = u[1][0]; pfa.uu[3] = u[1][1];
        pfb.uu[0] = u[2][0]; pfb.uu[1] = u[2][1]; pfb.uu[2] = u[3][0]; pfb.uu[3] = u[3][1];

        // ---- O^T[d][q] += V^T[d][key] · P^T ; row sums via ones-MFMA ----
        #pragma unroll
        for (int kk = 0; kk < 2; ++kk) {
            const s8v pf = kk ? pfb.s : pfa.s;
            sacc = __builtin_amdgcn_mfma_f32_16x16x32_bf16(onef, pf, sacc, 0, 0, 0);
            const int ko = ((kk * 4 + quad) ^ l8) * 8;
            #pragma unroll
            for (int j = 0; j < 4; ++j) {
                const s8v vf = *(const s8v*)(VsB + (j * 16 + l16) * 64 + ko);
                oacc[j] = __builtin_amdgcn_mfma_f32_16x16x32_bf16(
                    vf, pf, oacc[j], 0, 0, 0);
            }
        }
    }

    // ---- denominator: every row of sacc holds the full sum for col q ----
    const float inv = 1.0f / sacc[0];

    __syncthreads();   // everyone done with K/V LDS; reuse all of Ks as Os
    short* Os = (short*)Ks;   // 128 rows x 64 shorts = 16 KB
    #pragma unroll
    for (int j = 0; j < 4; ++j) {
        union { unsigned uu[2]; s4v s; } ov;
        ov.uu[0] = pk2(oacc[j][0] * inv, oacc[j][1] * inv);
        ov.uu[1] = pk2(oacc[j][2] * inv, oacc[j][3] * inv);
        const int pc = ((j * 2 + (quad >> 1)) ^ l8) * 8 + (quad & 1) * 4;
        *(s4v*)(Os + (wave * 16 + l16) * 64 + pc) = ov.s;
    }
    bar_lds();

    // ---- coalesced store: LDS swizzle cancels the output chunk swizzle ----
    const int row = tid >> 2;            // 0..127
    const int cb  = (tid & 3) * 2;       // two physical chunks per thread
    #pragma unroll
    for (int c4 = 0; c4 < 2; ++c4) {
        const int pcc = cb + c4;
        const s8v tt = *(const s8v*)(Os + row * 64 + pcc * 8);
        *(s8v*)(O + (size_t)(b * SEQ + q0 + row) * EMB + h * DHEAD + pcc * 8) = tt;
    }
}

extern "C" void kernel_launch(void* const* d_in, const int* in_sizes, int n_in,
                              void* d_out, int out_size, void* d_ws, size_t ws_size,
                              hipStream_t stream)
{
    const float* x  = (const float*)d_in[0];
    const float* Wq = (const float*)d_in[1];
    const float* bq = (const float*)d_in[2];
    const float* Wk = (const float*)d_in[3];
    const float* bk = (const float*)d_in[4];
    const float* Wv = (const float*)d_in[5];
    const float* bv = (const float*)d_in[6];
    const float* Wo = (const float*)d_in[7];
    const float* bo = (const float*)d_in[8];
    float* out = (float*)d_out;   // fp32 output

    short* xb  = (short*)d_ws;                       // 4096x1024 bf16, swizzled
    short* Wqb = xb  + (size_t)MTOT * EMB;           // swizzled
    short* Wkb = Wqb + (size_t)EMB * EMB;
    short* Wvb = Wkb + (size_t)EMB * EMB;
    short* Wob = Wvb + (size_t)EMB * EMB;
    short* Qw  = Wob + (size_t)EMB * EMB;            // [token][1024] (Q: plain;
                                                     //  then O: swizzled)
    short* Kw  = Qw  + (size_t)MTOT * EMB;           // [token][1024] plain
    short* Vtw = Kw  + (size_t)MTOT * EMB;           // [b][h][d][s] plain

    cvt_swz<<<dim3(512, 5), 256, 0, stream>>>(x, Wq, Wk, Wv, Wo,
                                              xb, Wqb, Wkb, Wvb, Wob);

    gemm_bb3<128, true><<<dim3(24, 32), 256, 0, stream>>>(
        xb, Wqb, Wkb, Wvb, bq, bk, bv, Qw, Kw, Vtw);

    attn_mfma7<<<dim3(BATCH * NHEAD * (SEQ / QT)), 512, 0, stream>>>(Qw, Kw, Vtw, Qw);

    gemm_bb3<64, false><<<dim3(16, 32), 256, 0, stream>>>(
        Qw, Wob, Wob, Wob, bo, bo, bo, out, out, out);
}

// Round 4
// 182.323 us; speedup vs baseline: 1.0634x; 1.0161x over previous
//
#include <hip/hip_runtime.h>
#include <hip/hip_bf16.h>

#define SEQ   2048
#define EMB   1024
#define NHEAD 16
#define DHEAD 64
#define BATCH 2
#define MTOT  (BATCH*SEQ)   // 4096
#define QT    128           // queries per attention block
#define KT    64            // keys per tile
#define NTILE (SEQ/KT)      // 32

typedef __attribute__((ext_vector_type(8))) short s8v;   // 8 bf16 (4 VGPRs)
typedef __attribute__((ext_vector_type(4))) short s4v;   // 4 bf16 (8 B)
typedef __attribute__((ext_vector_type(4))) float f4v;   // mfma accum

__device__ __forceinline__ short f2b(float f) {
    union { float fl; unsigned u; } v; v.fl = f;
    unsigned u = v.u;
    u = (u + 0x7fffu + ((u >> 16) & 1u)) >> 16;   // round-to-nearest-even
    return (short)u;
}
// packed fp32x2 -> bf16x2 (v_cvt_pk_bf16_f32); rounded values also feed the
// softmax denominator (consistency => rounding-mode-agnostic).
__device__ __forceinline__ unsigned pk2(float a, float b) {
    union { __hip_bfloat162 h; unsigned u; } c;
    c.h = __float22bfloat162_rn(float2{a, b});
    return c.u;
}

#if __has_builtin(__builtin_amdgcn_exp2f)
__device__ __forceinline__ float exp2_fast(float x) { return __builtin_amdgcn_exp2f(x); }
#else
__device__ __forceinline__ float exp2_fast(float x) { return exp2f(x); }
#endif

// gfx950 cross-lane half-swaps: dst upper part <-> src lower part.
__device__ __forceinline__ void pl32swap(unsigned &a, unsigned &b) {
    asm("v_permlane32_swap_b32 %0, %1" : "+v"(a), "+v"(b));
}
__device__ __forceinline__ void pl16swap(unsigned &a, unsigned &b) {
    asm("v_permlane16_swap_b32 %0, %1" : "+v"(a), "+v"(b));
}

// Raw workgroup barrier: LDS-visibility only (lgkmcnt drain), does NOT drain
// vmcnt — outstanding global prefetch loads stay in flight across it.
__device__ __forceinline__ void bar_lds() {
    asm volatile("s_waitcnt lgkmcnt(0)\n\ts_barrier" ::: "memory");
}

// async global->LDS DMA, 16 B/lane; LDS dest = wave-uniform base + lane*16.
__device__ __forceinline__ void gl_lds16(const short* g, short* l) {
    __builtin_amdgcn_global_load_lds(
        (const __attribute__((address_space(1))) void*)g,
        (__attribute__((address_space(3))) void*)l, 16, 0, 0);
}

// ---- fp32 -> bf16 convert + chunk swizzle ----
// Output rows are 1024 bf16 = 16 aligned 128B groups of 8 16B-chunks.
// Chunk c of row r is stored at slot (c&~7) | ((c&7) ^ (r&7)) so that
// global_load_lds' contiguous DMA lands a bank-uniform LDS image.
__global__ __launch_bounds__(256)
void cvt_swz(const float* __restrict__ s0, const float* __restrict__ s1,
             const float* __restrict__ s2, const float* __restrict__ s3,
             const float* __restrict__ s4,
             short* __restrict__ d0, short* __restrict__ d1,
             short* __restrict__ d2, short* __restrict__ d3,
             short* __restrict__ d4)
{
    const int seg = blockIdx.y;
    const float* s = seg == 0 ? s0 : seg == 1 ? s1 : seg == 2 ? s2 : seg == 3 ? s3 : s4;
    short*       d = seg == 0 ? d0 : seg == 1 ? d1 : seg == 2 ? d2 : seg == 3 ? d3 : d4;
    const int nchunk = (seg == 0 ? MTOT * EMB : EMB * EMB) / 8;   // 16B chunks
    const int stride = gridDim.x * 256;
    for (int i = blockIdx.x * 256 + threadIdx.x; i < nchunk; i += stride) {
        const int row = i >> 7;         // 128 chunks per 1024-col row
        const int c   = i & 127;
        const float4 v0 = *(const float4*)(s + (size_t)i * 8);
        const float4 v1 = *(const float4*)(s + (size_t)i * 8 + 4);
        s8v o;
        o[0] = f2b(v0.x); o[1] = f2b(v0.y); o[2] = f2b(v0.z); o[3] = f2b(v0.w);
        o[4] = f2b(v1.x); o[5] = f2b(v1.y); o[6] = f2b(v1.z); o[7] = f2b(v1.w);
        const int cp = (c & ~7) | ((c & 7) ^ (row & 7));
        *(s8v*)(d + (size_t)row * EMB + cp * 8) = o;
    }
}

// NT GEMM via global_load_lds (m97 structure): C = A*W^T + bias.
// A, W are bf16 with swizzled 16B chunks (see cvt_swz). LDS rows unpadded
// (128 B); frag reads address slot (kk*4+quad)^(l16&7) -> bank-uniform.
// FUSED3: 3 matrices (QKV); mat 2 writes V transposed per-head [b][h][d][s].
// mat 0 (Q) output is prescaled by 0.125*log2(e) so attention uses exp2.
template<int NT, bool FUSED3>
__global__ __launch_bounds__(256, 3)
void gemm_bb3(const short* __restrict__ A,
              const short* __restrict__ W0, const short* __restrict__ W1, const short* __restrict__ W2,
              const float* __restrict__ B0, const float* __restrict__ B1, const float* __restrict__ B2,
              void* __restrict__ C0, void* __restrict__ C1, void* __restrict__ C2)
{
    constexpr int JN = NT / 32;
    const int K = EMB, N = EMB;
    const int ntiles = EMB / NT;
    const int mat = blockIdx.x / ntiles;
    const int n0  = (blockIdx.x % ntiles) * NT;
    const int m0  = blockIdx.y * 128;
    const short* W  = (mat == 0) ? W0 : (mat == 1 ? W1 : W2);
    const float* Bi = (mat == 0) ? B0 : (mat == 1 ? B1 : B2);
    void*        C  = (mat == 0) ? C0 : (mat == 1 ? C1 : C2);
    const float qscale = (FUSED3 && mat == 0) ? 0.18033688f : 1.0f;  // 1/8*log2e

    __shared__ __align__(16) short As[128 * 64];
    __shared__ __align__(16) short Ws[NT * 64];

    const int tid  = threadIdx.x;
    const int lane = tid & 63;
    const int wave = tid >> 6;
    const int quad = lane >> 4;
    const int l16  = lane & 15;
    const int l8   = l16 & 7;
    const int wm   = wave >> 1;
    const int wn   = wave & 1;

    f4v acc[4][JN] = {};

    const int srow = lane >> 3;    // staging row within 8-row group
    const int scol = (lane & 7) * 8;

    for (int k0 = 0; k0 < K; k0 += 64) {
        // ---- async DMA staging: A rows wave*32.., W rows wave*(NT/4).. ----
        #pragma unroll
        for (int p = 0; p < 4; ++p) {
            const int rbase = wave * 32 + p * 8;
            gl_lds16(A + (size_t)(m0 + rbase + srow) * K + k0 + scol,
                     As + rbase * 64);
        }
        #pragma unroll
        for (int p = 0; p < NT / 32; ++p) {
            const int rbase = wave * (NT / 4) + p * 8;
            gl_lds16(W + (size_t)(n0 + rbase + srow) * K + k0 + scol,
                     Ws + rbase * 64);
        }
        __syncthreads();   // drains the DMA (vmcnt) + barrier

        #pragma unroll
        for (int kk = 0; kk < 2; ++kk) {
            const int slot = ((kk * 4 + quad) ^ l8) * 8;
            s8v af[4], wf[JN];
            #pragma unroll
            for (int i = 0; i < 4; ++i)
                af[i] = *(const s8v*)(As + (wm * 64 + i * 16 + l16) * 64 + slot);
            #pragma unroll
            for (int j = 0; j < JN; ++j)
                wf[j] = *(const s8v*)(Ws + (wn * (NT / 2) + j * 16 + l16) * 64 + slot);
            #pragma unroll
            for (int i = 0; i < 4; ++i)
                #pragma unroll
                for (int j = 0; j < JN; ++j)
                    acc[i][j] = __builtin_amdgcn_mfma_f32_16x16x32_bf16(
                        af[i], wf[j], acc[i][j], 0, 0, 0);
        }
        __syncthreads();   // all waves done reading before next overwrite
    }

    // C/D layout: col = lane&15 (n), row = quad*4+reg (m)   [m89-verified]
    #pragma unroll
    for (int j = 0; j < JN; ++j) {
        const int n = n0 + wn * (NT / 2) + j * 16 + l16;
        const float bv = Bi[n];
        #pragma unroll
        for (int i = 0; i < 4; ++i) {
            const int mb = m0 + wm * 64 + i * 16 + quad * 4;
            if (FUSED3 && mat == 2) {
                const int bb = mb >> 11, s = mb & 2047;
                s4v ov;
                #pragma unroll
                for (int rr = 0; rr < 4; ++rr) ov[rr] = f2b(acc[i][j][rr] + bv);
                *(s4v*)((short*)C + ((size_t)(bb * 1024 + n)) * SEQ + s) = ov;
            } else if (FUSED3) {
                #pragma unroll
                for (int rr = 0; rr < 4; ++rr)
                    ((short*)C)[(size_t)(mb + rr) * N + n] = f2b((acc[i][j][rr] + bv) * qscale);
            } else {
                #pragma unroll
                for (int rr = 0; rr < 4; ++rr)
                    ((float*)C)[(size_t)(mb + rr) * N + n] = acc[i][j][rr] + bv;
            }
        }
    }
}

// MFMA flash attention v8.
// vs v7: PV lags one tile (T15 pipeline). At tile t the body is
// QK(t) -> softmax(t)  INTERLEAVED WITH  PV(t-1), which are independent
// instruction streams (softmax = trans/VALU pipe; PV = ds_read + matrix
// pipe), so the matrix pipe stays fed during exp2/pack/swap instead of
// idling (v7: MfmaUtil 32% / VALUBusy 50%, strictly serial chain).
// Mechanics: V is TRIPLE-buffered in LDS (PV(t-1) reads Vs[(t-1)%3] while
// DMA(t+1) writes Vs[(t+1)%3] — distinct mod 3); K stays double-buffered
// (consumed by QK(t) immediately). Only cross-iteration regs: pf_prev
// (2 s8v). t=0 peeled so the steady-state body is branchless (a branch
// between softmax and PV would block scheduler interleave).
__global__ __launch_bounds__(512, 4)
void attn_mfma8(const short* Q, const short* __restrict__ Kg,
                const short* __restrict__ Vt, short* O)
{
    // dispatch i -> XCD i&7 (round-robin). Give each XCD 4 (b,h) combos.
    const int i    = blockIdx.x;          // 512 blocks
    const int xcd  = i & 7;
    const int slot = i >> 3;              // 0..63
    const int combo = xcd * 4 + (slot >> 4);   // (b,h) 0..31
    const int qb = slot & 15;                  // 16 q-blocks per (b,h)
    const int h  = combo & 15;
    const int b  = combo >> 4;
    const int q0 = qb * QT;

    const int tid  = threadIdx.x;
    const int lane = tid & 63;
    const int wave = tid >> 6;            // 0..7
    const int quad = lane >> 4;
    const int l16  = lane & 15;
    const int l8   = l16 & 7;

    __shared__ __align__(16) short Ks[2][64 * 64];   // [key][d] swizzled image
    __shared__ __align__(16) short Vs[3][64 * 64];   // [d][key] swizzled image

    // Q B-frags (prescaled by 0.125*log2e): wave handles 16 q-rows
    s8v qf[2];
    #pragma unroll
    for (int kk = 0; kk < 2; ++kk)
        qf[kk] = *(const s8v*)(Q + (size_t)(b * SEQ + q0 + wave * 16 + l16) * EMB
                                 + h * DHEAD + kk * 32 + quad * 8);

    f4v oacc[4] = {};   // [j: d-block] -> O^T[d][q]
    f4v sacc    = {};   // ones-MFMA row sums (col = q, all rows equal)
    s8v onef;
    #pragma unroll
    for (int e = 0; e < 8; ++e) onef[e] = (short)0x3F80;   // bf16 1.0

    // ---- DMA staging setup: lane (r,c) covers row r, physical chunk c ----
    const int r = lane >> 3, c = lane & 7;
    const int sc8 = (c ^ r) * 8;               // pre-swizzled source chunk
    const bool isK = wave < 4;
    const int wrow = (wave & 3) * 16;          // 16 rows per stager wave
    const size_t kbase = (size_t)(b * SEQ) * EMB + h * DHEAD;
    const size_t vbase = (size_t)((b * NHEAD + h) * DHEAD) * SEQ;
    const short* gsrc = isK ? Kg + kbase + (size_t)(wrow + r) * EMB + sc8
                            : Vt + vbase + (size_t)(wrow + r) * SEQ + sc8;
    const size_t gstep8 = isK ? (size_t)8 * EMB : (size_t)8 * SEQ;  // +8 rows
    const size_t tstep  = isK ? (size_t)KT * EMB : (size_t)KT;      // +1 tile
    short* const lbK = (short*)Ks + wrow * 64;
    short* const lbV = (short*)Vs + wrow * 64;

    // prologue: issue DMA for tile 0 -> Ks[0]/Vs[0]
    {
        short* l0 = isK ? lbK : lbV;
        gl_lds16(gsrc,          l0);
        gl_lds16(gsrc + gstep8, l0 + 8 * 64);
    }
    const short* gnext = gsrc + tstep;

    s8v pfA_prev, pfB_prev;   // P B-frags of tile t-1

    // ---- common tile pieces (macros keep one straight-line body) ----
#define QK_BLOCK(KSB)                                                        \
    f4v scv[4] = {};                                                         \
    _Pragma("unroll")                                                        \
    for (int kk = 0; kk < 2; ++kk) {                                         \
        const int ko = ((kk * 4 + quad) ^ l8) * 8;                           \
        s8v kf[4];                                                           \
        _Pragma("unroll")                                                    \
        for (int j = 0; j < 4; ++j)                                          \
            kf[j] = *(const s8v*)((KSB) + (j * 16 + l16) * 64 + ko);         \
        _Pragma("unroll")                                                    \
        for (int j = 0; j < 4; ++j)                                          \
            scv[j] = __builtin_amdgcn_mfma_f32_16x16x32_bf16(                \
                kf[j], qf[kk], scv[j], 0, 0, 0);                             \
    }

#define SM_BLOCK()                                                           \
    unsigned u[4][2];                                                        \
    _Pragma("unroll")                                                        \
    for (int j = 0; j < 4; ++j) {                                            \
        u[j][0] = pk2(exp2_fast(scv[j][0]), exp2_fast(scv[j][1]));           \
        u[j][1] = pk2(exp2_fast(scv[j][2]), exp2_fast(scv[j][3]));           \
    }                                                                        \
    _Pragma("unroll")                                                        \
    for (int r2 = 0; r2 < 2; ++r2) {                                         \
        pl32swap(u[0][r2], u[1][r2]);                                        \
        pl32swap(u[2][r2], u[3][r2]);                                        \
        pl16swap(u[0][r2], u[1][r2]);                                        \
        pl16swap(u[2][r2], u[3][r2]);                                        \
    }                                                                        \
    union { unsigned uu[4]; s8v s; } pfa, pfb;                               \
    pfa.uu[0] = u[0][0]; pfa.uu[1] = u[0][1];                                \
    pfa.uu[2] = u[1][0]; pfa.uu[3] = u[1][1];                                \
    pfb.uu[0] = u[2][0]; pfb.uu[1] = u[2][1];                                \
    pfb.uu[2] = u[3][0]; pfb.uu[3] = u[3][1];

#define PV_BLOCK(VSB)                                                        \
    _Pragma("unroll")                                                        \
    for (int kk = 0; kk < 2; ++kk) {                                         \
        const s8v pf = kk ? pfB_prev : pfA_prev;                             \
        sacc = __builtin_amdgcn_mfma_f32_16x16x32_bf16(onef, pf, sacc, 0, 0, 0); \
        const int ko = ((kk * 4 + quad) ^ l8) * 8;                           \
        _Pragma("unroll")                                                    \
        for (int j = 0; j < 4; ++j) {                                        \
            const s8v vf = *(const s8v*)((VSB) + (j * 16 + l16) * 64 + ko);  \
            oacc[j] = __builtin_amdgcn_mfma_f32_16x16x32_bf16(               \
                vf, pf, oacc[j], 0, 0, 0);                                   \
        }                                                                    \
    }

    // ---- peeled t = 0: QK + softmax only (no PV yet) ----
    {
        __syncthreads();   // tile 0 landed
        // issue DMA(1) -> Ks[1]/Vs[1]
        short* ldst = (isK ? lbK : lbV) + 64 * 64;
        gl_lds16(gnext,          ldst);
        gl_lds16(gnext + gstep8, ldst + 8 * 64);
        gnext += tstep;

        QK_BLOCK((const short*)Ks)
        SM_BLOCK()
        pfA_prev = pfa.s; pfB_prev = pfb.s;
    }

    // ---- steady state t = 1..31: QK(t) + [softmax(t) ∥ PV(t-1)] ----
    for (int t = 1; t < NTILE; ++t) {
        __syncthreads();   // tile t landed; all reads of buffers t-2 done
        const int tp1 = t + 1;
        if (tp1 < NTILE) {
            short* ldst = isK ? lbK + (tp1 & 1) * (64 * 64)
                              : lbV + (tp1 % 3) * (64 * 64);
            gl_lds16(gnext,          ldst);
            gl_lds16(gnext + gstep8, ldst + 8 * 64);
            gnext += tstep;
        }
        const short* KsB = (const short*)Ks + (t & 1) * (64 * 64);
        const short* VsB = (const short*)Vs + ((t - 1) % 3) * (64 * 64);

        QK_BLOCK(KsB)
        SM_BLOCK()
        PV_BLOCK(VsB)      // independent of SM_BLOCK -> scheduler interleaves
        pfA_prev = pfa.s; pfB_prev = pfb.s;
    }

    // ---- epilogue: PV(31) ----
    {
        const short* VsB = (const short*)Vs + ((NTILE - 1) % 3) * (64 * 64);
        PV_BLOCK(VsB)
    }
#undef QK_BLOCK
#undef SM_BLOCK
#undef PV_BLOCK

    // ---- denominator: every row of sacc holds the full sum for col q ----
    const float inv = 1.0f / sacc[0];

    __syncthreads();   // everyone done with K/V LDS; reuse Ks region as Os
    short* Os = (short*)Ks;   // 128 rows x 64 shorts = 16 KB
    #pragma unroll
    for (int j = 0; j < 4; ++j) {
        union { unsigned uu[2]; s4v s; } ov;
        ov.uu[0] = pk2(oacc[j][0] * inv, oacc[j][1] * inv);
        ov.uu[1] = pk2(oacc[j][2] * inv, oacc[j][3] * inv);
        const int pc = ((j * 2 + (quad >> 1)) ^ l8) * 8 + (quad & 1) * 4;
        *(s4v*)(Os + (wave * 16 + l16) * 64 + pc) = ov.s;
    }
    bar_lds();

    // ---- coalesced store: LDS swizzle cancels the output chunk swizzle ----
    const int row = tid >> 2;            // 0..127
    const int cb  = (tid & 3) * 2;       // two physical chunks per thread
    #pragma unroll
    for (int c4 = 0; c4 < 2; ++c4) {
        const int pcc = cb + c4;
        const s8v tt = *(const s8v*)(Os + row * 64 + pcc * 8);
        *(s8v*)(O + (size_t)(b * SEQ + q0 + row) * EMB + h * DHEAD + pcc * 8) = tt;
    }
}

extern "C" void kernel_launch(void* const* d_in, const int* in_sizes, int n_in,
                              void* d_out, int out_size, void* d_ws, size_t ws_size,
                              hipStream_t stream)
{
    const float* x  = (const float*)d_in[0];
    const float* Wq = (const float*)d_in[1];
    const float* bq = (const float*)d_in[2];
    const float* Wk = (const float*)d_in[3];
    const float* bk = (const float*)d_in[4];
    const float* Wv = (const float*)d_in[5];
    const float* bv = (const float*)d_in[6];
    const float* Wo = (const float*)d_in[7];
    const float* bo = (const float*)d_in[8];
    float* out = (float*)d_out;   // fp32 output

    short* xb  = (short*)d_ws;                       // 4096x1024 bf16, swizzled
    short* Wqb = xb  + (size_t)MTOT * EMB;           // swizzled
    short* Wkb = Wqb + (size_t)EMB * EMB;
    short* Wvb = Wkb + (size_t)EMB * EMB;
    short* Wob = Wvb + (size_t)EMB * EMB;
    short* Qw  = Wob + (size_t)EMB * EMB;            // [token][1024] (Q: plain;
                                                     //  then O: swizzled)
    short* Kw  = Qw  + (size_t)MTOT * EMB;           // [token][1024] plain
    short* Vtw = Kw  + (size_t)MTOT * EMB;           // [b][h][d][s] plain

    cvt_swz<<<dim3(512, 5), 256, 0, stream>>>(x, Wq, Wk, Wv, Wo,
                                              xb, Wqb, Wkb, Wvb, Wob);

    gemm_bb3<128, true><<<dim3(24, 32), 256, 0, stream>>>(
        xb, Wqb, Wkb, Wvb, bq, bk, bv, Qw, Kw, Vtw);

    attn_mfma8<<<dim3(BATCH * NHEAD * (SEQ / QT)), 512, 0, stream>>>(Qw, Kw, Vtw, Qw);

    gemm_bb3<64, false><<<dim3(16, 32), 256, 0, stream>>>(
        Qw, Wob, Wob, Wob, bo, bo, bo, out, out, out);
}